// Round 8
// baseline (73.736 us; speedup 1.0000x reference)
//
#include <hip/hip_runtime.h>

#define N   32
#define NN  1024

// One WAVE (64 lanes) per batch element. Lane (ty,tx) owns a 4x4 cell tile in
// registers (interior of a 6x6 block g). Halo = border of g, fetched from the
// 8 neighboring lanes' registers via __shfl (ds_bpermute crossbar; no LDS, no
// fence, no bank conflicts). Edge lanes mask their missing halo to INF.
//
// Per sweep: ONE halo exchange + TWO min3-fused rasters, with the raster PAIR
// ALTERNATING by sweep parity (fast-sweeping style):
//   even sweep: SE (i asc, j asc) then NW (i desc, j desc)
//   odd  sweep: NE (i desc, j asc) then SW (i asc, j desc)
// Direction algebra: a row-major raster aligns ALL steps into later rows plus
// one horizontal direction. {SE,NW} covers down+E / up+W monotone segments;
// {NE,SW} covers up+E / down+W. Alternating covers every semi-monotone path
// segment within 2 sweeps — R5 showed 4-rasters-per-sweep cuts sweep count
// ~0.6x; this gets that coverage at half the per-sweep cost.
//
// Termination: 'changed' accumulates over both rasters of a sweep; RELAX
// always examines all 8 neighbors, so a zero-change sweep (fresh halos at
// sweep start, zero changes anywhere => halos stayed current) certifies the
// Bellman inequality everywhere -> fixpoint. Raster order is irrelevant to
// the certificate.
//
// Exactness: every assigned value is an fp-fold (((0+w)+w)+...) of a source
// path; monotone-decreasing chaotic iteration from INF converges to the
// unique fixpoint = min-over-paths fold = the reference's Dijkstra distances
// bitwise (absmax=0 across R1/R3/R4/R5/R6/R7 under six different orders).
// LDS only in the epilogue (pred/path) with the single-wave
// __threadfence_block pattern (R2 showed the compiler fence is mandatory).
__global__ __launch_bounds__(64, 1) void dijkstra_path_kernel(
    const float* __restrict__ weights, float* __restrict__ out)
{
    const int b    = blockIdx.x;
    const int lane = threadIdx.x & 63;
    const int ty   = lane >> 3;        // tile row 0..7
    const int tx   = lane & 7;         // tile col 0..7
    const int y0   = ty << 2;          // tile origin (global cell coords)
    const int x0   = tx << 2;

    __shared__ int   pred[NN];         // 4 KB
    __shared__ float pathf[NN];        // 4 KB

    const float INF = __builtin_huge_valf();

    // ---- pathf = 0 ----
    #pragma unroll
    for (int k = 0; k < 16; ++k) pathf[lane + k * 64] = 0.0f;

    // ---- weights tile -> registers (float4 rows) ----
    float w[4][4];
    const float* wb = weights + b * NN;
    #pragma unroll
    for (int i = 0; i < 4; ++i) {
        const float4 v = *(const float4*)(wb + (y0 + i) * N + x0);
        w[i][0] = v.x; w[i][1] = v.y; w[i][2] = v.z; w[i][3] = v.w;
    }

    // ---- register state: 6x6 (interior = my 4x4 tile, border = halo) ----
    float g[6][6];
    #pragma unroll
    for (int i = 0; i < 6; ++i)
        #pragma unroll
        for (int j = 0; j < 6; ++j) g[i][j] = INF;
    if (lane == 0) g[1][1] = 0.0f;     // source (0,0)

    const bool hT = (ty > 0), hB = (ty < 7), hL = (tx > 0), hR = (tx < 7);

    // fetch halo from neighbor lanes' registers; mask off-grid edges to INF
#define EXCHANGE()                                                            \
    {                                                                         \
        float tT[4], tB[4], tL[4], tR[4];                                     \
        _Pragma("unroll")                                                     \
        for (int j = 0; j < 4; ++j) tT[j] = __shfl(g[4][1 + j], lane - 8);    \
        _Pragma("unroll")                                                     \
        for (int j = 0; j < 4; ++j) tB[j] = __shfl(g[1][1 + j], lane + 8);    \
        _Pragma("unroll")                                                     \
        for (int i = 0; i < 4; ++i) tL[i] = __shfl(g[1 + i][4], lane - 1);    \
        _Pragma("unroll")                                                     \
        for (int i = 0; i < 4; ++i) tR[i] = __shfl(g[1 + i][1], lane + 1);    \
        const float cTL = __shfl(g[4][4], lane - 9);                          \
        const float cTR = __shfl(g[4][1], lane - 7);                          \
        const float cBL = __shfl(g[1][4], lane + 7);                          \
        const float cBR = __shfl(g[1][1], lane + 9);                          \
        _Pragma("unroll")                                                     \
        for (int j = 0; j < 4; ++j) {                                         \
            g[0][1 + j] = hT ? tT[j] : INF;                                   \
            g[5][1 + j] = hB ? tB[j] : INF;                                   \
        }                                                                     \
        _Pragma("unroll")                                                     \
        for (int i = 0; i < 4; ++i) {                                         \
            g[1 + i][0] = hL ? tL[i] : INF;                                   \
            g[1 + i][5] = hR ? tR[i] : INF;                                   \
        }                                                                     \
        g[0][0] = (hT && hL) ? cTL : INF;                                     \
        g[0][5] = (hT && hR) ? cTR : INF;                                     \
        g[5][0] = (hB && hL) ? cBL : INF;                                     \
        g[5][5] = (hB && hR) ? cBR : INF;                                     \
    }

    // min3-fused 8-neighbor relax (checks ALL 8 neighbors regardless of order)
#define RELAX(i, j)                                                           \
    {                                                                         \
        const float old = g[(i)][(j)];                                        \
        const float a = fminf(fminf(g[(i)-1][(j)-1], g[(i)-1][(j)]),          \
                              g[(i)-1][(j)+1]);                               \
        const float c = fminf(fminf(g[(i)][(j)-1], g[(i)][(j)+1]),            \
                              g[(i)+1][(j)-1]);                               \
        const float e = fminf(g[(i)+1][(j)], g[(i)+1][(j)+1]);                \
        const float m = fminf(fminf(a, c), e);                                \
        const float nv = m + w[(i)-1][(j)-1];                                 \
        changed |= (nv < old);                                                \
        g[(i)][(j)] = fminf(old, nv);                                         \
    }

    // ---- relaxation sweeps (alternating raster pairs) ----
    for (int it = 0; it < 384; ++it) {
        bool changed = false;
        EXCHANGE()
        if ((it & 1) == 0) {
            // SE: i asc, j asc
            #pragma unroll
            for (int i = 1; i <= 4; ++i)
                #pragma unroll
                for (int j = 1; j <= 4; ++j) RELAX(i, j)
            // NW: i desc, j desc
            #pragma unroll
            for (int i = 4; i >= 1; --i)
                #pragma unroll
                for (int j = 4; j >= 1; --j) RELAX(i, j)
        } else {
            // NE: i desc, j asc
            #pragma unroll
            for (int i = 4; i >= 1; --i)
                #pragma unroll
                for (int j = 1; j <= 4; ++j) RELAX(i, j)
            // SW: i asc, j desc
            #pragma unroll
            for (int i = 1; i <= 4; ++i)
                #pragma unroll
                for (int j = 4; j >= 1; --j) RELAX(i, j)
        }
        if (!__any((int)changed)) break;
    }
#undef RELAX

    // refresh halo once more so pred argmin sees final neighbor values
    EXCHANGE()
#undef EXCHANGE

    // ---- predecessors: argmin over 8 neighbors of fp(dist_u + w_v), DIRS order ----
    const int dy[8] = {-1, 1, 0, 0, -1, -1, 1, 1};
    const int dx[8] = { 0, 0,-1, 1, -1,  1,-1, 1};
    #pragma unroll
    for (int i = 0; i < 4; ++i)
        #pragma unroll
        for (int j = 0; j < 4; ++j) {
            const int yy = y0 + i, xx = x0 + j;
            const int t  = yy * N + xx;
            int p = 0;
            if (t != 0) {
                float best = INF;
                #pragma unroll
                for (int k = 0; k < 8; ++k) {
                    const float u = g[1 + i + dy[k]][1 + j + dx[k]];  // OOB -> INF
                    const float c = u + w[i][j];
                    if (c < best) { best = c; p = (yy + dy[k]) * N + (xx + dx[k]); }
                }
            }
            pred[t] = p;
        }
    __threadfence_block();             // publish pred (compiler fence; wave DS in-order)

    // ---- serial backtrack from (31,31); pred[0]==0 is the fixed point ----
    if (lane == 0) {
        int cur = NN - 1;
        pathf[cur] = 1.0f;
        for (int s = 0; s < NN && cur != 0; ++s) {
            cur = pred[cur];
            pathf[cur] = 1.0f;
        }
    }
    __threadfence_block();             // publish lane 0's path writes

    // ---- write output (float4 rows) ----
    float* ob = out + b * NN;
    #pragma unroll
    for (int i = 0; i < 4; ++i) {
        const int t = (y0 + i) * N + x0;
        const float4 v = *(const float4*)&pathf[t];
        *(float4*)(ob + t) = v;
    }
}

extern "C" void kernel_launch(void* const* d_in, const int* in_sizes, int n_in,
                              void* d_out, int out_size, void* d_ws, size_t ws_size,
                              hipStream_t stream) {
    const float* w = (const float*)d_in[0];
    float* out = (float*)d_out;
    const int b = in_sizes[0] / NN;   // 128
    dijkstra_path_kernel<<<dim3(b), dim3(64), 0, stream>>>(w, out);
}